// Round 1
// baseline (327.886 us; speedup 1.0000x reference)
//
#include <hip/hip_runtime.h>
#include <hip/hip_bf16.h>
#include <stdint.h>

typedef __bf16 bf16_t;
typedef __bf16 bf16x8 __attribute__((ext_vector_type(8)));
typedef float  f32x4  __attribute__((ext_vector_type(4)));

#define DM    1024
#define NH    16
#define HD    64
#define SEQ   2048
#define BATCH 2
#define BS    (BATCH*SEQ)   // 4096
#define NQKV  (3*DM)        // 3072

#define GLOAD_LDS16(g, l) \
  __builtin_amdgcn_global_load_lds((const __attribute__((address_space(1))) void*)(g), \
                                   (__attribute__((address_space(3))) void*)(l), 16, 0, 0)

__device__ __forceinline__ f32x4 mfma16(bf16x8 a, bf16x8 b, f32x4 c) {
  return __builtin_amdgcn_mfma_f32_16x16x32_bf16(a, b, c, 0, 0, 0);
}

// ---------------- cast fp32 -> bf16 (8 elems/thread, vectorized) ----------------
__global__ void k_cast(const float* __restrict__ in, bf16_t* __restrict__ out, int n) {
  int i = (blockIdx.x * blockDim.x + threadIdx.x) * 8;
  if (i >= n) return;
  float4 a = *(const float4*)(in + i);
  float4 b = *(const float4*)(in + i + 4);
  bf16x8 o;
  o[0] = (bf16_t)a.x; o[1] = (bf16_t)a.y; o[2] = (bf16_t)a.z; o[3] = (bf16_t)a.w;
  o[4] = (bf16_t)b.x; o[5] = (bf16_t)b.y; o[6] = (bf16_t)b.z; o[7] = (bf16_t)b.w;
  *(bf16x8*)(out + i) = o;
}

// ---------------- rope cos/sin table: [SEQ][32] float2 ----------------
__global__ void k_rope_table(float2* __restrict__ rt) {
  int idx = blockIdx.x * blockDim.x + threadIdx.x;
  if (idx >= SEQ * 32) return;
  int s = idx >> 5, i = idx & 31;
  float inv = powf(10000.0f, -(float)(2 * i) / 64.0f);
  float ang = (float)s * inv;
  rt[idx] = make_float2(cosf(ang), sinf(ang));
}

// ---------------- GEMM: C[M,N] = A[M,K] * B[N,K]^T + bias ----------------
// 128x128 tile, BK=32, 256 thr (4 waves, 2x2 wave grid, 64x64 each, 4x4 frags)
template<int OUT_F32>
__global__ __launch_bounds__(256) void k_gemm_bt(
    const bf16_t* __restrict__ A, const bf16_t* __restrict__ B,
    const float* __restrict__ bias, void* __restrict__ Cout,
    int M, int N, int K)
{
  __shared__ __align__(16) bf16_t As[128 * 32];
  __shared__ __align__(16) bf16_t Bs[128 * 32];
  const int tid  = threadIdx.x;
  const int lane = tid & 63;
  const int wave = tid >> 6;
  const int wr = wave >> 1, wc = wave & 1;
  const int m0 = blockIdx.y * 128, n0 = blockIdx.x * 128;

  f32x4 acc[4][4];
  #pragma unroll
  for (int i = 0; i < 4; ++i)
    #pragma unroll
    for (int j = 0; j < 4; ++j)
      #pragma unroll
      for (int e = 0; e < 4; ++e) acc[i][j][e] = 0.0f;

  // staging: wave stages rows [wave*32, wave*32+32) of A and B tiles
  const int srow = wave * 32;
  const int lrow = lane >> 2;          // 0..15
  const int lk   = (lane & 3) * 8;     // k element offset
  const bf16_t* ga0 = A + (size_t)(m0 + srow +      lrow) * K + lk;
  const bf16_t* ga1 = A + (size_t)(m0 + srow + 16 + lrow) * K + lk;
  const bf16_t* gb0 = B + (size_t)(n0 + srow +      lrow) * K + lk;
  const bf16_t* gb1 = B + (size_t)(n0 + srow + 16 + lrow) * K + lk;
  bf16_t* la0 = &As[(srow)      * 32];
  bf16_t* la1 = &As[(srow + 16) * 32];
  bf16_t* lb0 = &Bs[(srow)      * 32];
  bf16_t* lb1 = &Bs[(srow + 16) * 32];

  const bf16_t* pa = &As[(wr * 64 + (lane & 15)) * 32 + (lane >> 4) * 8];
  const bf16_t* pb = &Bs[(wc * 64 + (lane & 15)) * 32 + (lane >> 4) * 8];

  for (int kt = 0; kt < K; kt += 32) {
    GLOAD_LDS16(ga0 + kt, la0);
    GLOAD_LDS16(ga1 + kt, la1);
    GLOAD_LDS16(gb0 + kt, lb0);
    GLOAD_LDS16(gb1 + kt, lb1);
    __syncthreads();
    bf16x8 af[4], bfr[4];
    #pragma unroll
    for (int t = 0; t < 4; ++t) af[t]  = *(const bf16x8*)(pa + t * 16 * 32);
    #pragma unroll
    for (int t = 0; t < 4; ++t) bfr[t] = *(const bf16x8*)(pb + t * 16 * 32);
    #pragma unroll
    for (int i = 0; i < 4; ++i)
      #pragma unroll
      for (int j = 0; j < 4; ++j)
        acc[i][j] = mfma16(af[i], bfr[j], acc[i][j]);
    __syncthreads();
  }

  // epilogue: row = m0+wr*64+i*16+(lane>>4)*4+e ; col = n0+wc*64+j*16+(lane&15)
  const int rbase = m0 + wr * 64 + ((lane >> 4) << 2);
  const int cbase = n0 + wc * 64 + (lane & 15);
  #pragma unroll
  for (int j = 0; j < 4; ++j) {
    const int c = cbase + j * 16;
    const float bv = bias[c];
    #pragma unroll
    for (int i = 0; i < 4; ++i) {
      #pragma unroll
      for (int e = 0; e < 4; ++e) {
        const int r = rbase + i * 16 + e;
        float v = acc[i][j][e] + bv;
        if (OUT_F32) ((float*)Cout)[(size_t)r * N + c] = v;
        else         ((bf16_t*)Cout)[(size_t)r * N + c] = (bf16_t)v;
      }
    }
  }
}

// ---------------- RoPE + head split + V transpose ----------------
// in: qkv [BS][3072] bf16   out: Q,K [B*H][SEQ][64], Vt [B*H][64][SEQ]
__global__ __launch_bounds__(256) void k_rope_transpose(
    const bf16_t* __restrict__ qkv, const float2* __restrict__ rt,
    bf16_t* __restrict__ Qo, bf16_t* __restrict__ Ko, bf16_t* __restrict__ Vt)
{
  __shared__ __align__(16) bf16_t vtile[64][80];
  const int st = blockIdx.x & 31;   // s-tile of 64
  const int bh = blockIdx.x >> 5;   // 0..31
  const int b  = bh >> 4, h = bh & 15;
  const int tid = threadIdx.x;
  const int sl = tid >> 2;          // 0..63
  const int dq = (tid & 3) * 16;    // d chunk
  const int spos = st * 64 + sl;
  const size_t base = ((size_t)(b * SEQ + spos)) * NQKV + h * HD + dq;

  bf16x8 q0v = *(const bf16x8*)&qkv[base];
  bf16x8 q1v = *(const bf16x8*)&qkv[base + 8];
  bf16x8 k0v = *(const bf16x8*)&qkv[base + DM];
  bf16x8 k1v = *(const bf16x8*)&qkv[base + DM + 8];
  bf16x8 v0v = *(const bf16x8*)&qkv[base + 2 * DM];
  bf16x8 v1v = *(const bf16x8*)&qkv[base + 2 * DM + 8];

  float qf[16], kf[16];
  #pragma unroll
  for (int e = 0; e < 8; ++e) {
    qf[e] = (float)q0v[e]; qf[8 + e] = (float)q1v[e];
    kf[e] = (float)k0v[e]; kf[8 + e] = (float)k1v[e];
  }
  #pragma unroll
  for (int p = 0; p < 8; ++p) {
    float2 cs = rt[spos * 32 + (dq >> 1) + p];
    float a = qf[2*p], bq_ = qf[2*p+1];
    qf[2*p]   = a * cs.x - bq_ * cs.y;
    qf[2*p+1] = a * cs.y + bq_ * cs.x;
    float c = kf[2*p], d = kf[2*p+1];
    kf[2*p]   = c * cs.x - d * cs.y;
    kf[2*p+1] = c * cs.y + d * cs.x;
  }
  bf16x8 oq0, oq1, ok0, ok1;
  #pragma unroll
  for (int e = 0; e < 8; ++e) {
    oq0[e] = (bf16_t)qf[e]; oq1[e] = (bf16_t)qf[8 + e];
    ok0[e] = (bf16_t)kf[e]; ok1[e] = (bf16_t)kf[8 + e];
  }
  const size_t qdst = ((size_t)bh * SEQ + spos) * HD + dq;
  *(bf16x8*)&Qo[qdst]     = oq0;
  *(bf16x8*)&Qo[qdst + 8] = oq1;
  *(bf16x8*)&Ko[qdst]     = ok0;
  *(bf16x8*)&Ko[qdst + 8] = ok1;

  *(bf16x8*)&vtile[sl][dq]     = v0v;
  *(bf16x8*)&vtile[sl][dq + 8] = v1v;
  __syncthreads();
  const int d  = tid >> 2;          // 0..63
  const int sc = (tid & 3) * 16;
  bf16x8 o0, o1;
  #pragma unroll
  for (int e = 0; e < 8; ++e) {
    o0[e] = vtile[sc + e][d];
    o1[e] = vtile[sc + 8 + e][d];
  }
  const size_t vdst = ((size_t)bh * HD + d) * SEQ + st * 64 + sc;
  *(bf16x8*)&Vt[vdst]     = o0;
  *(bf16x8*)&Vt[vdst + 8] = o1;
}

// ---------------- flash attention ----------------
// grid: BH*32 blocks; 4 waves/block; wave owns 16 q rows; KVBLK=32
__global__ __launch_bounds__(256) void k_attn(
    const bf16_t* __restrict__ Q, const bf16_t* __restrict__ K,
    const bf16_t* __restrict__ Vt, bf16_t* __restrict__ O)
{
  __shared__ __align__(16) bf16_t plds[4][16 * 32];
  const int tid = threadIdx.x, lane = tid & 63, wave = tid >> 6;
  const int qt = blockIdx.x & 31;
  const int bh = blockIdx.x >> 5;
  const int b  = bh >> 4, h = bh & 15;
  const int q0 = qt * 64 + wave * 16;

  const bf16_t* Qb = Q  + (size_t)bh * SEQ * HD;
  const bf16_t* Kb = K  + (size_t)bh * SEQ * HD;
  const bf16_t* Vb = Vt + (size_t)bh * HD * SEQ;

  const int c16 = lane & 15;
  const int g   = lane >> 4;    // 0..3

  bf16x8 qa0 = *(const bf16x8*)&Qb[(q0 + c16) * HD + g * 8];
  bf16x8 qa1 = *(const bf16x8*)&Qb[(q0 + c16) * HD + 32 + g * 8];

  f32x4 oacc[4];
  float m_[4], l_[4];
  #pragma unroll
  for (int nt = 0; nt < 4; ++nt)
    #pragma unroll
    for (int e = 0; e < 4; ++e) oacc[nt][e] = 0.0f;
  #pragma unroll
  for (int j = 0; j < 4; ++j) { m_[j] = -1e30f; l_[j] = 0.0f; }

  const int ntile = (q0 + 15) / 32 + 1;
  bf16_t* pw = &plds[wave][0];

  for (int t = 0; t < ntile; ++t) {
    const int kv0 = t * 32;
    f32x4 s0, s1;
    #pragma unroll
    for (int e = 0; e < 4; ++e) { s0[e] = 0.0f; s1[e] = 0.0f; }
    {
      const bf16_t* kr = &Kb[(kv0 + c16) * HD + g * 8];
      bf16x8 kb0 = *(const bf16x8*)(kr);
      bf16x8 kb1 = *(const bf16x8*)(kr + 32);
      s0 = mfma16(qa0, kb0, s0);
      s0 = mfma16(qa1, kb1, s0);
      const bf16_t* kr2 = kr + 16 * HD;
      bf16x8 kb2 = *(const bf16x8*)(kr2);
      bf16x8 kb3 = *(const bf16x8*)(kr2 + 32);
      s1 = mfma16(qa0, kb2, s1);
      s1 = mfma16(qa1, kb3, s1);
    }
    #pragma unroll
    for (int j = 0; j < 4; ++j) {
      const int r  = q0 + g * 4 + j;
      const int ca = kv0 + c16, cb = kv0 + 16 + c16;
      float va = (ca <= r) ? s0[j] * 0.125f : -1e30f;
      float vb = (cb <= r) ? s1[j] * 0.125f : -1e30f;
      float mx = fmaxf(va, vb);
      #pragma unroll
      for (int d = 1; d < 16; d <<= 1) mx = fmaxf(mx, __shfl_xor(mx, d));
      const float mn = fmaxf(m_[j], mx);
      const float alpha = __expf(m_[j] - mn);
      const float pa_ = __expf(va - mn);
      const float pb_ = __expf(vb - mn);
      float ps = pa_ + pb_;
      #pragma unroll
      for (int d = 1; d < 16; d <<= 1) ps += __shfl_xor(ps, d);
      l_[j] = l_[j] * alpha + ps;
      m_[j] = mn;
      #pragma unroll
      for (int nt = 0; nt < 4; ++nt) oacc[nt][j] *= alpha;
      pw[(g * 4 + j) * 32 + c16]      = (bf16_t)pa_;
      pw[(g * 4 + j) * 32 + 16 + c16] = (bf16_t)pb_;
    }
    bf16x8 pfrag = *(const bf16x8*)&pw[c16 * 32 + g * 8];
    #pragma unroll
    for (int nt = 0; nt < 4; ++nt) {
      bf16x8 vb8 = *(const bf16x8*)&Vb[(size_t)(nt * 16 + c16) * SEQ + kv0 + g * 8];
      oacc[nt] = mfma16(pfrag, vb8, oacc[nt]);
    }
  }

  #pragma unroll
  for (int nt = 0; nt < 4; ++nt) {
    #pragma unroll
    for (int j = 0; j < 4; ++j) {
      const int r = q0 + g * 4 + j;
      float v = oacc[nt][j] / l_[j];
      O[((size_t)(b * SEQ + r)) * DM + h * HD + nt * 16 + c16] = (bf16_t)v;
    }
  }
}

// ---------------- launch ----------------
extern "C" void kernel_launch(void* const* d_in, const int* in_sizes, int n_in,
                              void* d_out, int out_size, void* d_ws, size_t ws_size,
                              hipStream_t stream)
{
  const float* x  = (const float*)d_in[0];
  const float* Wq = (const float*)d_in[1];
  const float* bq = (const float*)d_in[2];
  const float* Wk = (const float*)d_in[3];
  const float* bk = (const float*)d_in[4];
  const float* Wv = (const float*)d_in[5];
  const float* bv = (const float*)d_in[6];
  const float* Wo = (const float*)d_in[7];
  const float* bo = (const float*)d_in[8];
  float* out = (float*)d_out;

  char* ws = (char*)d_ws;
  size_t off = 0;
  auto alloc = [&](size_t bytes) { char* p = ws + off; off += (bytes + 255) & ~255ULL; return p; };
  bf16_t* xb   = (bf16_t*)alloc((size_t)BS * DM * 2);
  bf16_t* Wcat = (bf16_t*)alloc((size_t)NQKV * DM * 2);
  bf16_t* Wob  = (bf16_t*)alloc((size_t)DM * DM * 2);
  float*  bcat = (float*)alloc((size_t)NQKV * 4);
  float2* rt   = (float2*)alloc((size_t)SEQ * 32 * 8);
  bf16_t* qkv  = (bf16_t*)alloc((size_t)BS * NQKV * 2);
  bf16_t* Qh   = (bf16_t*)alloc((size_t)BS * DM * 2);
  bf16_t* Kh   = (bf16_t*)alloc((size_t)BS * DM * 2);
  bf16_t* Vth  = (bf16_t*)alloc((size_t)BS * DM * 2);
  bf16_t* Oh   = (bf16_t*)alloc((size_t)BS * DM * 2);
  (void)ws_size; (void)in_sizes; (void)n_in; (void)out_size;

  k_cast<<<BS * DM / 8 / 256, 256, 0, stream>>>(x, xb, BS * DM);
  k_cast<<<DM * DM / 8 / 256, 256, 0, stream>>>(Wq, Wcat, DM * DM);
  k_cast<<<DM * DM / 8 / 256, 256, 0, stream>>>(Wk, Wcat + DM * DM, DM * DM);
  k_cast<<<DM * DM / 8 / 256, 256, 0, stream>>>(Wv, Wcat + 2 * DM * DM, DM * DM);
  k_cast<<<DM * DM / 8 / 256, 256, 0, stream>>>(Wo, Wob, DM * DM);
  hipMemcpyAsync(bcat,          bq, DM * 4, hipMemcpyDeviceToDevice, stream);
  hipMemcpyAsync(bcat + DM,     bk, DM * 4, hipMemcpyDeviceToDevice, stream);
  hipMemcpyAsync(bcat + 2 * DM, bv, DM * 4, hipMemcpyDeviceToDevice, stream);
  k_rope_table<<<SEQ * 32 / 256, 256, 0, stream>>>(rt);

  dim3 g1(NQKV / 128, BS / 128);
  k_gemm_bt<0><<<g1, 256, 0, stream>>>(xb, Wcat, bcat, qkv, BS, NQKV, DM);
  k_rope_transpose<<<32 * 32, 256, 0, stream>>>(qkv, rt, Qh, Kh, Vth);
  k_attn<<<32 * 32, 256, 0, stream>>>(Qh, Kh, Vth, Oh);
  dim3 g2(DM / 128, BS / 128);
  k_gemm_bt<1><<<g2, 256, 0, stream>>>(Oh, Wob, bo, out, BS, DM, DM);
}

// Round 2
// 245.882 us; speedup vs baseline: 1.3335x; 1.3335x over previous
//
#include <hip/hip_runtime.h>
#include <hip/hip_bf16.h>
#include <stdint.h>

typedef __bf16 bf16_t;
typedef __bf16 bf16x4 __attribute__((ext_vector_type(4)));
typedef __bf16 bf16x8 __attribute__((ext_vector_type(8)));
typedef float  f32x4  __attribute__((ext_vector_type(4)));

#define DM    1024
#define NH    16
#define HD    64
#define SEQ   2048
#define BATCH 2
#define BS    (BATCH*SEQ)   // 4096
#define NQKV  (3*DM)        // 3072

#define GLOAD_LDS16(g, l) \
  __builtin_amdgcn_global_load_lds((const __attribute__((address_space(1))) void*)(g), \
                                   (__attribute__((address_space(3))) void*)(l), 16, 0, 0)

__device__ __forceinline__ f32x4 mfma16(bf16x8 a, bf16x8 b, f32x4 c) {
  return __builtin_amdgcn_mfma_f32_16x16x32_bf16(a, b, c, 0, 0, 0);
}

// ---------------- cast fp32 -> bf16 (8 elems/thread, vectorized) ----------------
__global__ void k_cast(const float* __restrict__ in, bf16_t* __restrict__ out, int n) {
  int i = (blockIdx.x * blockDim.x + threadIdx.x) * 8;
  if (i >= n) return;
  float4 a = *(const float4*)(in + i);
  float4 b = *(const float4*)(in + i + 4);
  bf16x8 o;
  o[0] = (bf16_t)a.x; o[1] = (bf16_t)a.y; o[2] = (bf16_t)a.z; o[3] = (bf16_t)a.w;
  o[4] = (bf16_t)b.x; o[5] = (bf16_t)b.y; o[6] = (bf16_t)b.z; o[7] = (bf16_t)b.w;
  *(bf16x8*)(out + i) = o;
}

// ---------------- rope cos/sin table: [SEQ][32] float2 ----------------
__global__ void k_rope_table(float2* __restrict__ rt) {
  int idx = blockIdx.x * blockDim.x + threadIdx.x;
  if (idx >= SEQ * 32) return;
  int s = idx >> 5, i = idx & 31;
  float inv = powf(10000.0f, -(float)(2 * i) / 64.0f);
  float ang = (float)s * inv;
  rt[idx] = make_float2(cosf(ang), sinf(ang));
}

// ---------------- GEMM: C[M,N] = A[M,K] * B[N,K]^T + bias ----------------
// 128x128 tile, BK=32, 256 thr (4 waves, 2x2 wave grid, 64x64 each, 4x4 frags)
template<int OUT_F32>
__global__ __launch_bounds__(256) void k_gemm_bt(
    const bf16_t* __restrict__ A, const bf16_t* __restrict__ B,
    const float* __restrict__ bias, void* __restrict__ Cout,
    int M, int N, int K)
{
  __shared__ __align__(16) bf16_t As[128 * 32];
  __shared__ __align__(16) bf16_t Bs[128 * 32];
  const int tid  = threadIdx.x;
  const int lane = tid & 63;
  const int wave = tid >> 6;
  const int wr = wave >> 1, wc = wave & 1;
  const int m0 = blockIdx.y * 128, n0 = blockIdx.x * 128;

  f32x4 acc[4][4];
  #pragma unroll
  for (int i = 0; i < 4; ++i)
    #pragma unroll
    for (int j = 0; j < 4; ++j)
      #pragma unroll
      for (int e = 0; e < 4; ++e) acc[i][j][e] = 0.0f;

  const int srow = wave * 32;
  const int lrow = lane >> 2;          // 0..15
  const int lk   = (lane & 3) * 8;     // k element offset
  const bf16_t* ga0 = A + (size_t)(m0 + srow +      lrow) * K + lk;
  const bf16_t* ga1 = A + (size_t)(m0 + srow + 16 + lrow) * K + lk;
  const bf16_t* gb0 = B + (size_t)(n0 + srow +      lrow) * K + lk;
  const bf16_t* gb1 = B + (size_t)(n0 + srow + 16 + lrow) * K + lk;
  bf16_t* la0 = &As[(srow)      * 32];
  bf16_t* la1 = &As[(srow + 16) * 32];
  bf16_t* lb0 = &Bs[(srow)      * 32];
  bf16_t* lb1 = &Bs[(srow + 16) * 32];

  const bf16_t* pa = &As[(wr * 64 + (lane & 15)) * 32 + (lane >> 4) * 8];
  const bf16_t* pb = &Bs[(wc * 64 + (lane & 15)) * 32 + (lane >> 4) * 8];

  for (int kt = 0; kt < K; kt += 32) {
    GLOAD_LDS16(ga0 + kt, la0);
    GLOAD_LDS16(ga1 + kt, la1);
    GLOAD_LDS16(gb0 + kt, lb0);
    GLOAD_LDS16(gb1 + kt, lb1);
    __syncthreads();
    bf16x8 af[4], bfr[4];
    #pragma unroll
    for (int t = 0; t < 4; ++t) af[t]  = *(const bf16x8*)(pa + t * 16 * 32);
    #pragma unroll
    for (int t = 0; t < 4; ++t) bfr[t] = *(const bf16x8*)(pb + t * 16 * 32);
    #pragma unroll
    for (int i = 0; i < 4; ++i)
      #pragma unroll
      for (int j = 0; j < 4; ++j)
        acc[i][j] = mfma16(af[i], bfr[j], acc[i][j]);
    __syncthreads();
  }

  const int rbase = m0 + wr * 64 + ((lane >> 4) << 2);
  const int cbase = n0 + wc * 64 + (lane & 15);
  #pragma unroll
  for (int j = 0; j < 4; ++j) {
    const int c = cbase + j * 16;
    const float bv = bias[c];
    #pragma unroll
    for (int i = 0; i < 4; ++i) {
      #pragma unroll
      for (int e = 0; e < 4; ++e) {
        const int r = rbase + i * 16 + e;
        float v = acc[i][j][e] + bv;
        if (OUT_F32) ((float*)Cout)[(size_t)r * N + c] = v;
        else         ((bf16_t*)Cout)[(size_t)r * N + c] = (bf16_t)v;
      }
    }
  }
}

// ---------------- RoPE + head split + V transpose ----------------
__global__ __launch_bounds__(256) void k_rope_transpose(
    const bf16_t* __restrict__ qkv, const float2* __restrict__ rt,
    bf16_t* __restrict__ Qo, bf16_t* __restrict__ Ko, bf16_t* __restrict__ Vt)
{
  __shared__ __align__(16) bf16_t vtile[64][80];
  const int st = blockIdx.x & 31;   // s-tile of 64
  const int bh = blockIdx.x >> 5;   // 0..31
  const int b  = bh >> 4, h = bh & 15;
  const int tid = threadIdx.x;
  const int sl = tid >> 2;          // 0..63
  const int dq = (tid & 3) * 16;    // d chunk
  const int spos = st * 64 + sl;
  const size_t base = ((size_t)(b * SEQ + spos)) * NQKV + h * HD + dq;

  bf16x8 q0v = *(const bf16x8*)&qkv[base];
  bf16x8 q1v = *(const bf16x8*)&qkv[base + 8];
  bf16x8 k0v = *(const bf16x8*)&qkv[base + DM];
  bf16x8 k1v = *(const bf16x8*)&qkv[base + DM + 8];
  bf16x8 v0v = *(const bf16x8*)&qkv[base + 2 * DM];
  bf16x8 v1v = *(const bf16x8*)&qkv[base + 2 * DM + 8];

  float qf[16], kf[16];
  #pragma unroll
  for (int e = 0; e < 8; ++e) {
    qf[e] = (float)q0v[e]; qf[8 + e] = (float)q1v[e];
    kf[e] = (float)k0v[e]; kf[8 + e] = (float)k1v[e];
  }
  #pragma unroll
  for (int p = 0; p < 8; ++p) {
    float2 cs = rt[spos * 32 + (dq >> 1) + p];
    float a = qf[2*p], bq_ = qf[2*p+1];
    qf[2*p]   = a * cs.x - bq_ * cs.y;
    qf[2*p+1] = a * cs.y + bq_ * cs.x;
    float c = kf[2*p], d = kf[2*p+1];
    kf[2*p]   = c * cs.x - d * cs.y;
    kf[2*p+1] = c * cs.y + d * cs.x;
  }
  bf16x8 oq0, oq1, ok0, ok1;
  #pragma unroll
  for (int e = 0; e < 8; ++e) {
    oq0[e] = (bf16_t)qf[e]; oq1[e] = (bf16_t)qf[8 + e];
    ok0[e] = (bf16_t)kf[e]; ok1[e] = (bf16_t)kf[8 + e];
  }
  const size_t qdst = ((size_t)bh * SEQ + spos) * HD + dq;
  *(bf16x8*)&Qo[qdst]     = oq0;
  *(bf16x8*)&Qo[qdst + 8] = oq1;
  *(bf16x8*)&Ko[qdst]     = ok0;
  *(bf16x8*)&Ko[qdst + 8] = ok1;

  *(bf16x8*)&vtile[sl][dq]     = v0v;
  *(bf16x8*)&vtile[sl][dq + 8] = v1v;
  __syncthreads();
  const int d  = tid >> 2;          // 0..63
  const int sc = (tid & 3) * 16;
  bf16x8 o0, o1;
  #pragma unroll
  for (int e = 0; e < 8; ++e) {
    o0[e] = vtile[sc + e][d];
    o1[e] = vtile[sc + 8 + e][d];
  }
  const size_t vdst = ((size_t)bh * HD + d) * SEQ + st * 64 + sc;
  *(bf16x8*)&Vt[vdst]     = o0;
  *(bf16x8*)&Vt[vdst + 8] = o1;
}

// ---------------- flash attention (swapped-QK^T, lane-local softmax) ----------------
// grid: 32 qtiles x 32 bh, heavy tiles first; 4 waves/block; wave owns 16 q rows;
// KVBLK=64. S^T = mfma(Kfrag, Qfrag): lane holds S[kv][q=lane&15], kv = 16u+4g+r.
// Softmax per lane: in-register 16-max + 2 shfl_xor. P^T redistributed via
// per-wave LDS tile [16][64+pad]. PV: O[d][q] with A=Vt rows, B=P^T.
__global__ __launch_bounds__(256) void k_attn(
    const bf16_t* __restrict__ Q, const bf16_t* __restrict__ K,
    const bf16_t* __restrict__ Vt, bf16_t* __restrict__ O)
{
  __shared__ __align__(16) bf16_t plds[4][16][68];
  const int tid = threadIdx.x, lane = tid & 63, wave = tid >> 6;
  const int qt = 31 - (blockIdx.x >> 5);   // heavy-first (LPT) ordering
  const int bh = blockIdx.x & 31;
  const int b  = bh >> 4, h = bh & 15;
  const int q0 = qt * 64 + wave * 16;
  const int c16 = lane & 15;
  const int g   = lane >> 4;               // 0..3
  const int q   = q0 + c16;

  const bf16_t* Qb = Q  + (size_t)bh * SEQ * HD;
  const bf16_t* Kb = K  + (size_t)bh * SEQ * HD;
  const bf16_t* Vb = Vt + (size_t)bh * HD * SEQ;

  // Q B-fragments (lane holds Q[q][k=g*8..+8] per k-half)
  bf16x8 qf0 = *(const bf16x8*)&Qb[(size_t)q * HD + g * 8];
  bf16x8 qf1 = *(const bf16x8*)&Qb[(size_t)q * HD + 32 + g * 8];

  f32x4 oacc[4];
  #pragma unroll
  for (int dblk = 0; dblk < 4; ++dblk)
    #pragma unroll
    for (int e = 0; e < 4; ++e) oacc[dblk][e] = 0.0f;
  float m_ = -1e30f, l_ = 0.0f;
  const float SC = 0.125f * 1.44269504088896f;  // 1/sqrt(64) * log2(e)

  const int ntile = qt + 1;
  bf16_t (*pl)[68] = plds[wave];

  for (int t = 0; t < ntile; ++t) {
    const int kv0 = t * 64;
    // ---- QK^T (swapped): st[u][r] = S[kv0+16u+4g+r][q] ----
    f32x4 st[4];
    #pragma unroll
    for (int u = 0; u < 4; ++u) {
      const bf16_t* kr = &Kb[(size_t)(kv0 + 16 * u + c16) * HD + g * 8];
      bf16x8 k0 = *(const bf16x8*)kr;
      bf16x8 k1 = *(const bf16x8*)(kr + 32);
      f32x4 z; z[0] = z[1] = z[2] = z[3] = 0.0f;
      z = mfma16(k0, qf0, z);
      z = mfma16(k1, qf1, z);
      st[u] = z;
    }
    // ---- mask + scale (exp2 domain) ----
    float pv[16];
    #pragma unroll
    for (int u = 0; u < 4; ++u)
      #pragma unroll
      for (int r = 0; r < 4; ++r) {
        const int kv = kv0 + 16 * u + 4 * g + r;
        pv[u * 4 + r] = (kv <= q) ? st[u][r] * SC : -1e30f;
      }
    // ---- row max: in-register tree + 2 shfl ----
    float ma = fmaxf(fmaxf(pv[0], pv[1]), fmaxf(pv[2], pv[3]));
    float mb = fmaxf(fmaxf(pv[4], pv[5]), fmaxf(pv[6], pv[7]));
    float mc = fmaxf(fmaxf(pv[8], pv[9]), fmaxf(pv[10], pv[11]));
    float md = fmaxf(fmaxf(pv[12], pv[13]), fmaxf(pv[14], pv[15]));
    float mx = fmaxf(fmaxf(ma, mb), fmaxf(mc, md));
    mx = fmaxf(mx, __shfl_xor(mx, 16));
    mx = fmaxf(mx, __shfl_xor(mx, 32));
    const float mn = fmaxf(m_, mx);
    const float alpha = exp2f(m_ - mn);
    // ---- exp + row sum ----
    #pragma unroll
    for (int i = 0; i < 16; ++i) pv[i] = exp2f(pv[i] - mn);
    float s0 = (pv[0] + pv[1]) + (pv[2] + pv[3]);
    float s1 = (pv[4] + pv[5]) + (pv[6] + pv[7]);
    float s2 = (pv[8] + pv[9]) + (pv[10] + pv[11]);
    float s3 = (pv[12] + pv[13]) + (pv[14] + pv[15]);
    float ps = (s0 + s1) + (s2 + s3);
    ps += __shfl_xor(ps, 16);
    ps += __shfl_xor(ps, 32);
    l_ = l_ * alpha + ps;
    m_ = mn;
    #pragma unroll
    for (int dblk = 0; dblk < 4; ++dblk)
      #pragma unroll
      for (int e = 0; e < 4; ++e) oacc[dblk][e] *= alpha;
    // ---- pack P -> bf16, LDS round-trip to A/B-operand layout ----
    #pragma unroll
    for (int u = 0; u < 4; ++u) {
      bf16x4 pk;
      #pragma unroll
      for (int r = 0; r < 4; ++r) pk[r] = (bf16_t)pv[u * 4 + r];
      *(bf16x4*)&pl[c16][16 * u + 4 * g] = pk;   // P[kv0+16u+4g+r][q] at [q][kvloc]
    }
    bf16x8 pf0 = *(const bf16x8*)&pl[c16][8 * g];        // P^T[q][kv = 0..31 slice]
    bf16x8 pf1 = *(const bf16x8*)&pl[c16][32 + 8 * g];   // P^T[q][kv = 32..63 slice]
    // ---- PV: oacc[dblk][r] = O[d = dblk*16+4g+r][q] ----
    #pragma unroll
    for (int dblk = 0; dblk < 4; ++dblk) {
      const bf16_t* vr = &Vb[(size_t)(dblk * 16 + c16) * SEQ + kv0 + g * 8];
      bf16x8 v0 = *(const bf16x8*)vr;
      bf16x8 v1 = *(const bf16x8*)(vr + 32);
      oacc[dblk] = mfma16(v0, pf0, oacc[dblk]);
      oacc[dblk] = mfma16(v1, pf1, oacc[dblk]);
    }
  }

  // ---- epilogue: O[q][d], d = dblk*16+4g+r (4 consecutive -> bf16x4 store) ----
  const float inv = 1.0f / l_;
  bf16_t* orow = O + ((size_t)(b * SEQ + q)) * DM + h * HD;
  #pragma unroll
  for (int dblk = 0; dblk < 4; ++dblk) {
    bf16x4 ov;
    #pragma unroll
    for (int r = 0; r < 4; ++r) ov[r] = (bf16_t)(oacc[dblk][r] * inv);
    *(bf16x4*)&orow[dblk * 16 + 4 * g] = ov;
  }
}

// ---------------- launch ----------------
extern "C" void kernel_launch(void* const* d_in, const int* in_sizes, int n_in,
                              void* d_out, int out_size, void* d_ws, size_t ws_size,
                              hipStream_t stream)
{
  const float* x  = (const float*)d_in[0];
  const float* Wq = (const float*)d_in[1];
  const float* bq = (const float*)d_in[2];
  const float* Wk = (const float*)d_in[3];
  const float* bk = (const float*)d_in[4];
  const float* Wv = (const float*)d_in[5];
  const float* bv = (const float*)d_in[6];
  const float* Wo = (const float*)d_in[7];
  const float* bo = (const float*)d_in[8];
  float* out = (float*)d_out;

  char* ws = (char*)d_ws;
  size_t off = 0;
  auto alloc = [&](size_t bytes) { char* p = ws + off; off += (bytes + 255) & ~255ULL; return p; };
  bf16_t* xb   = (bf16_t*)alloc((size_t)BS * DM * 2);
  bf16_t* Wcat = (bf16_t*)alloc((size_t)NQKV * DM * 2);
  bf16_t* Wob  = (bf16_t*)alloc((size_t)DM * DM * 2);
  float*  bcat = (float*)alloc((size_t)NQKV * 4);
  float2* rt   = (float2*)alloc((size_t)SEQ * 32 * 8);
  bf16_t* qkv  = (bf16_t*)alloc((size_t)BS * NQKV * 2);
  bf16_t* Qh   = (bf16_t*)alloc((size_t)BS * DM * 2);
  bf16_t* Kh   = (bf16_t*)alloc((size_t)BS * DM * 2);
  bf16_t* Vth  = (bf16_t*)alloc((size_t)BS * DM * 2);
  bf16_t* Oh   = (bf16_t*)alloc((size_t)BS * DM * 2);
  (void)ws_size; (void)in_sizes; (void)n_in; (void)out_size;

  k_cast<<<BS * DM / 8 / 256, 256, 0, stream>>>(x, xb, BS * DM);
  k_cast<<<DM * DM / 8 / 256, 256, 0, stream>>>(Wq, Wcat, DM * DM);
  k_cast<<<DM * DM / 8 / 256, 256, 0, stream>>>(Wk, Wcat + DM * DM, DM * DM);
  k_cast<<<DM * DM / 8 / 256, 256, 0, stream>>>(Wv, Wcat + 2 * DM * DM, DM * DM);
  k_cast<<<DM * DM / 8 / 256, 256, 0, stream>>>(Wo, Wob, DM * DM);
  hipMemcpyAsync(bcat,          bq, DM * 4, hipMemcpyDeviceToDevice, stream);
  hipMemcpyAsync(bcat + DM,     bk, DM * 4, hipMemcpyDeviceToDevice, stream);
  hipMemcpyAsync(bcat + 2 * DM, bv, DM * 4, hipMemcpyDeviceToDevice, stream);
  k_rope_table<<<SEQ * 32 / 256, 256, 0, stream>>>(rt);

  dim3 g1(NQKV / 128, BS / 128);
  k_gemm_bt<0><<<g1, 256, 0, stream>>>(xb, Wcat, bcat, qkv, BS, NQKV, DM);
  k_rope_transpose<<<32 * 32, 256, 0, stream>>>(qkv, rt, Qh, Kh, Vth);
  k_attn<<<32 * 32, 256, 0, stream>>>(Qh, Kh, Vth, Oh);
  dim3 g2(DM / 128, BS / 128);
  k_gemm_bt<1><<<g2, 256, 0, stream>>>(Oh, Wob, bo, out, BS, DM, DM);
}

// Round 3
// 152.903 us; speedup vs baseline: 2.1444x; 1.6081x over previous
//
#include <hip/hip_runtime.h>
#include <hip/hip_bf16.h>
#include <stdint.h>

typedef __bf16 bf16_t;
typedef __bf16 bf16x4 __attribute__((ext_vector_type(4)));
typedef __bf16 bf16x8 __attribute__((ext_vector_type(8)));
typedef float  f32x4  __attribute__((ext_vector_type(4)));

#define DM    1024
#define NH    16
#define HD    64
#define SEQ   2048
#define BATCH 2
#define BS    (BATCH*SEQ)   // 4096
#define NQKV  (3*DM)        // 3072

#define GLOAD_LDS16(g, l) \
  __builtin_amdgcn_global_load_lds((const __attribute__((address_space(1))) void*)(g), \
                                   (__attribute__((address_space(3))) void*)(l), 16, 0, 0)

__device__ __forceinline__ f32x4 mfma16(bf16x8 a, bf16x8 b, f32x4 c) {
  return __builtin_amdgcn_mfma_f32_16x16x32_bf16(a, b, c, 0, 0, 0);
}

// ---------------- cast fp32 -> bf16 (8 elems/thread, vectorized) ----------------
__global__ void k_cast(const float* __restrict__ in, bf16_t* __restrict__ out, int n) {
  int i = (blockIdx.x * blockDim.x + threadIdx.x) * 8;
  if (i >= n) return;
  float4 a = *(const float4*)(in + i);
  float4 b = *(const float4*)(in + i + 4);
  bf16x8 o;
  o[0] = (bf16_t)a.x; o[1] = (bf16_t)a.y; o[2] = (bf16_t)a.z; o[3] = (bf16_t)a.w;
  o[4] = (bf16_t)b.x; o[5] = (bf16_t)b.y; o[6] = (bf16_t)b.z; o[7] = (bf16_t)b.w;
  *(bf16x8*)(out + i) = o;
}

// ---------------- rope cos/sin table: [SEQ][32] float2 ----------------
__global__ void k_rope_table(float2* __restrict__ rt) {
  int idx = blockIdx.x * blockDim.x + threadIdx.x;
  if (idx >= SEQ * 32) return;
  int s = idx >> 5, i = idx & 31;
  float inv = powf(10000.0f, -(float)(2 * i) / 64.0f);
  float ang = (float)s * inv;
  rt[idx] = make_float2(cosf(ang), sinf(ang));
}

// ---------------- GEMM: C[M,N] = A[M,K] * B[N,K]^T + bias ----------------
template<int OUT_F32>
__global__ __launch_bounds__(256) void k_gemm_bt(
    const bf16_t* __restrict__ A, const bf16_t* __restrict__ B,
    const float* __restrict__ bias, void* __restrict__ Cout,
    int M, int N, int K)
{
  __shared__ __align__(16) bf16_t As[128 * 32];
  __shared__ __align__(16) bf16_t Bs[128 * 32];
  const int tid  = threadIdx.x;
  const int lane = tid & 63;
  const int wave = tid >> 6;
  const int wr = wave >> 1, wc = wave & 1;
  const int m0 = blockIdx.y * 128, n0 = blockIdx.x * 128;

  f32x4 acc[4][4];
  #pragma unroll
  for (int i = 0; i < 4; ++i)
    #pragma unroll
    for (int j = 0; j < 4; ++j)
      #pragma unroll
      for (int e = 0; e < 4; ++e) acc[i][j][e] = 0.0f;

  const int srow = wave * 32;
  const int lrow = lane >> 2;
  const int lk   = (lane & 3) * 8;
  const bf16_t* ga0 = A + (size_t)(m0 + srow +      lrow) * K + lk;
  const bf16_t* ga1 = A + (size_t)(m0 + srow + 16 + lrow) * K + lk;
  const bf16_t* gb0 = B + (size_t)(n0 + srow +      lrow) * K + lk;
  const bf16_t* gb1 = B + (size_t)(n0 + srow + 16 + lrow) * K + lk;
  bf16_t* la0 = &As[(srow)      * 32];
  bf16_t* la1 = &As[(srow + 16) * 32];
  bf16_t* lb0 = &Bs[(srow)      * 32];
  bf16_t* lb1 = &Bs[(srow + 16) * 32];

  const bf16_t* pa = &As[(wr * 64 + (lane & 15)) * 32 + (lane >> 4) * 8];
  const bf16_t* pb = &Bs[(wc * 64 + (lane & 15)) * 32 + (lane >> 4) * 8];

  for (int kt = 0; kt < K; kt += 32) {
    GLOAD_LDS16(ga0 + kt, la0);
    GLOAD_LDS16(ga1 + kt, la1);
    GLOAD_LDS16(gb0 + kt, lb0);
    GLOAD_LDS16(gb1 + kt, lb1);
    __syncthreads();
    bf16x8 af[4], bfr[4];
    #pragma unroll
    for (int t = 0; t < 4; ++t) af[t]  = *(const bf16x8*)(pa + t * 16 * 32);
    #pragma unroll
    for (int t = 0; t < 4; ++t) bfr[t] = *(const bf16x8*)(pb + t * 16 * 32);
    #pragma unroll
    for (int i = 0; i < 4; ++i)
      #pragma unroll
      for (int j = 0; j < 4; ++j)
        acc[i][j] = mfma16(af[i], bfr[j], acc[i][j]);
    __syncthreads();
  }

  const int rbase = m0 + wr * 64 + ((lane >> 4) << 2);
  const int cbase = n0 + wc * 64 + (lane & 15);
  #pragma unroll
  for (int j = 0; j < 4; ++j) {
    const int c = cbase + j * 16;
    const float bv = bias[c];
    #pragma unroll
    for (int i = 0; i < 4; ++i) {
      #pragma unroll
      for (int e = 0; e < 4; ++e) {
        const int r = rbase + i * 16 + e;
        float v = acc[i][j][e] + bv;
        if (OUT_F32) ((float*)Cout)[(size_t)r * N + c] = v;
        else         ((bf16_t*)Cout)[(size_t)r * N + c] = (bf16_t)v;
      }
    }
  }
}

// ---------------- RoPE + head split + V transpose ----------------
__global__ __launch_bounds__(256) void k_rope_transpose(
    const bf16_t* __restrict__ qkv, const float2* __restrict__ rt,
    bf16_t* __restrict__ Qo, bf16_t* __restrict__ Ko, bf16_t* __restrict__ Vt)
{
  __shared__ __align__(16) bf16_t vtile[64][80];
  const int st = blockIdx.x & 31;
  const int bh = blockIdx.x >> 5;
  const int b  = bh >> 4, h = bh & 15;
  const int tid = threadIdx.x;
  const int sl = tid >> 2;
  const int dq = (tid & 3) * 16;
  const int spos = st * 64 + sl;
  const size_t base = ((size_t)(b * SEQ + spos)) * NQKV + h * HD + dq;

  bf16x8 q0v = *(const bf16x8*)&qkv[base];
  bf16x8 q1v = *(const bf16x8*)&qkv[base + 8];
  bf16x8 k0v = *(const bf16x8*)&qkv[base + DM];
  bf16x8 k1v = *(const bf16x8*)&qkv[base + DM + 8];
  bf16x8 v0v = *(const bf16x8*)&qkv[base + 2 * DM];
  bf16x8 v1v = *(const bf16x8*)&qkv[base + 2 * DM + 8];

  float qf[16], kf[16];
  #pragma unroll
  for (int e = 0; e < 8; ++e) {
    qf[e] = (float)q0v[e]; qf[8 + e] = (float)q1v[e];
    kf[e] = (float)k0v[e]; kf[8 + e] = (float)k1v[e];
  }
  #pragma unroll
  for (int p = 0; p < 8; ++p) {
    float2 cs = rt[spos * 32 + (dq >> 1) + p];
    float a = qf[2*p], bq_ = qf[2*p+1];
    qf[2*p]   = a * cs.x - bq_ * cs.y;
    qf[2*p+1] = a * cs.y + bq_ * cs.x;
    float c = kf[2*p], d = kf[2*p+1];
    kf[2*p]   = c * cs.x - d * cs.y;
    kf[2*p+1] = c * cs.y + d * cs.x;
  }
  bf16x8 oq0, oq1, ok0, ok1;
  #pragma unroll
  for (int e = 0; e < 8; ++e) {
    oq0[e] = (bf16_t)qf[e]; oq1[e] = (bf16_t)qf[8 + e];
    ok0[e] = (bf16_t)kf[e]; ok1[e] = (bf16_t)kf[8 + e];
  }
  const size_t qdst = ((size_t)bh * SEQ + spos) * HD + dq;
  *(bf16x8*)&Qo[qdst]     = oq0;
  *(bf16x8*)&Qo[qdst + 8] = oq1;
  *(bf16x8*)&Ko[qdst]     = ok0;
  *(bf16x8*)&Ko[qdst + 8] = ok1;

  *(bf16x8*)&vtile[sl][dq]     = v0v;
  *(bf16x8*)&vtile[sl][dq + 8] = v1v;
  __syncthreads();
  const int d  = tid >> 2;
  const int sc = (tid & 3) * 16;
  bf16x8 o0, o1;
  #pragma unroll
  for (int e = 0; e < 8; ++e) {
    o0[e] = vtile[sc + e][d];
    o1[e] = vtile[sc + 8 + e][d];
  }
  const size_t vdst = ((size_t)bh * HD + d) * SEQ + st * 64 + sc;
  *(bf16x8*)&Vt[vdst]     = o0;
  *(bf16x8*)&Vt[vdst + 8] = o1;
}

// ---------------- flash attention (LDS-staged K/V, double-buffered, swapped QK^T) ----
// 4 waves/block, wave owns 16 q rows, KVBLK=64. K/V tiles staged via global_load_lds
// (linear dest, XOR-swizzled global source: byte ^= ((row&7)<<4)); ds_read uses the
// same XOR. 2-phase pipeline: stage(t+1) issued before compute(t), one barrier/tile.
// Softmax lane-local (swapped MFMA) + T13 defer-rescale.
__global__ __launch_bounds__(256) void k_attn(
    const bf16_t* __restrict__ Q, const bf16_t* __restrict__ K,
    const bf16_t* __restrict__ Vt, bf16_t* __restrict__ O)
{
  __shared__ __align__(16) bf16_t kbuf[2][64 * 64];
  __shared__ __align__(16) bf16_t vbuf[2][64 * 64];
  __shared__ __align__(16) bf16_t plds[4][16][68];
  const int tid = threadIdx.x, lane = tid & 63, wave = tid >> 6;
  const int qt = 31 - (blockIdx.x >> 5);   // heavy-first (LPT)
  const int bh = blockIdx.x & 31;
  const int b  = bh >> 4, h = bh & 15;
  const int q0 = qt * 64 + wave * 16;
  const int c16 = lane & 15;
  const int g   = lane >> 4;
  const int q   = q0 + c16;

  const bf16_t* Qb = Q  + (size_t)bh * SEQ * HD;
  const bf16_t* Kb = K  + (size_t)bh * SEQ * HD;
  const bf16_t* Vb = Vt + (size_t)bh * HD * SEQ;

  bf16x8 qf0 = *(const bf16x8*)&Qb[(size_t)q * HD + g * 8];
  bf16x8 qf1 = *(const bf16x8*)&Qb[(size_t)q * HD + 32 + g * 8];

  f32x4 oacc[4];
  #pragma unroll
  for (int dblk = 0; dblk < 4; ++dblk)
    #pragma unroll
    for (int e = 0; e < 4; ++e) oacc[dblk][e] = 0.0f;
  float m_ = -1e30f, l_ = 0.0f;
  const float SC = 0.125f * 1.44269504088896f;  // 1/sqrt(64) * log2(e)

  const int ntile = qt + 1;
  bf16_t (*pl)[68] = plds[wave];

  // stage tile tt into buffer bb: K rows [kv0..kv0+64) x 64d, V rows d x 64kv.
  // linear LDS dest (wave-uniform base; HW adds lane*16); global source
  // pre-swizzled so that swizzled ds_read below sees row-major data.
  auto stage = [&](int tt, int bb) {
    const int kvs = tt * 64;
    #pragma unroll
    for (int c = 0; c < 2; ++c) {
      const int base = wave * 1024 + c * 4096;        // byte base (wave-uniform)
      const int off  = base + lane * 16;              // this lane's dest byte
      const int row  = off >> 7;
      const int colb = (off & 127) ^ ((row & 7) << 4);
      GLOAD_LDS16(&Kb[(size_t)(kvs + row) * HD + (colb >> 1)], &kbuf[bb][base >> 1]);
      GLOAD_LDS16(&Vb[(size_t)row * SEQ + kvs + (colb >> 1)], &vbuf[bb][base >> 1]);
    }
  };

  stage(0, 0);
  __syncthreads();
  int cur = 0;

  // lane-constant swizzled fragment element offsets (r&7 == c16&7 for all reads)
  const int sw = (c16 & 7) << 4;
  const int e0 = ((16 * g) ^ sw) >> 1;          // k/v lo-half (bytes 0..63)
  const int e1 = ((64 + 16 * g) ^ sw) >> 1;     // hi-half (bytes 64..127)

  for (int t = 0; t < ntile; ++t) {
    if (t + 1 < ntile) stage(t + 1, cur ^ 1);

    // ---- QK^T (swapped): st[u][r] = S[t*64+16u+4g+r][q] ----
    const bf16_t* kb = kbuf[cur];
    f32x4 st[4];
    #pragma unroll
    for (int u = 0; u < 4; ++u) {
      const int r = 16 * u + c16;
      bf16x8 k0 = *(const bf16x8*)&kb[r * 64 + e0];
      bf16x8 k1 = *(const bf16x8*)&kb[r * 64 + e1];
      f32x4 z; z[0] = z[1] = z[2] = z[3] = 0.0f;
      z = mfma16(k0, qf0, z);
      z = mfma16(k1, qf1, z);
      st[u] = z;
    }

    // ---- V fragments (independent of softmax; issue early) ----
    const bf16_t* vb = vbuf[cur];
    bf16x8 vf[4][2];
    #pragma unroll
    for (int dblk = 0; dblk < 4; ++dblk) {
      const int rv = dblk * 16 + c16;
      vf[dblk][0] = *(const bf16x8*)&vb[rv * 64 + e0];
      vf[dblk][1] = *(const bf16x8*)&vb[rv * 64 + e1];
    }

    // ---- mask + scale (exp2 domain); only diagonal tile needs the compare ----
    float pv[16];
    if (t == qt) {
      const int kv0 = t * 64;
      #pragma unroll
      for (int u = 0; u < 4; ++u)
        #pragma unroll
        for (int r = 0; r < 4; ++r) {
          const int kv = kv0 + 16 * u + 4 * g + r;
          pv[u * 4 + r] = (kv <= q) ? st[u][r] * SC : -1e30f;
        }
    } else {
      #pragma unroll
      for (int u = 0; u < 4; ++u)
        #pragma unroll
        for (int r = 0; r < 4; ++r)
          pv[u * 4 + r] = st[u][r] * SC;
    }

    // ---- row max: in-register tree + 2 shfl ----
    float ma = fmaxf(fmaxf(pv[0], pv[1]), fmaxf(pv[2], pv[3]));
    float mb = fmaxf(fmaxf(pv[4], pv[5]), fmaxf(pv[6], pv[7]));
    float mc = fmaxf(fmaxf(pv[8], pv[9]), fmaxf(pv[10], pv[11]));
    float md = fmaxf(fmaxf(pv[12], pv[13]), fmaxf(pv[14], pv[15]));
    float mx = fmaxf(fmaxf(ma, mb), fmaxf(mc, md));
    mx = fmaxf(mx, __shfl_xor(mx, 16));
    mx = fmaxf(mx, __shfl_xor(mx, 32));

    // ---- T13 defer-rescale: only rescale when some row's max grew past THR ----
    if (__any(mx - m_ > 12.0f)) {
      const float mn = fmaxf(m_, mx);
      const float alpha = exp2f(m_ - mn);
      l_ *= alpha;
      #pragma unroll
      for (int dblk = 0; dblk < 4; ++dblk)
        #pragma unroll
        for (int e = 0; e < 4; ++e) oacc[dblk][e] *= alpha;
      m_ = mn;
    }

    // ---- exp + row sum ----
    #pragma unroll
    for (int i = 0; i < 16; ++i) pv[i] = exp2f(pv[i] - m_);
    float s0 = (pv[0] + pv[1]) + (pv[2] + pv[3]);
    float s1 = (pv[4] + pv[5]) + (pv[6] + pv[7]);
    float s2 = (pv[8] + pv[9]) + (pv[10] + pv[11]);
    float s3 = (pv[12] + pv[13]) + (pv[14] + pv[15]);
    float ps = (s0 + s1) + (s2 + s3);
    ps += __shfl_xor(ps, 16);
    ps += __shfl_xor(ps, 32);
    l_ += ps;

    // ---- pack P -> bf16, per-wave LDS round-trip to B-operand layout ----
    #pragma unroll
    for (int u = 0; u < 4; ++u) {
      bf16x4 pk;
      #pragma unroll
      for (int r = 0; r < 4; ++r) pk[r] = (bf16_t)pv[u * 4 + r];
      *(bf16x4*)&pl[c16][16 * u + 4 * g] = pk;
    }
    bf16x8 pf0 = *(const bf16x8*)&pl[c16][8 * g];
    bf16x8 pf1 = *(const bf16x8*)&pl[c16][32 + 8 * g];

    // ---- PV: oacc[dblk][r] = O[d = dblk*16+4g+r][q] ----
    #pragma unroll
    for (int dblk = 0; dblk < 4; ++dblk) {
      oacc[dblk] = mfma16(vf[dblk][0], pf0, oacc[dblk]);
      oacc[dblk] = mfma16(vf[dblk][1], pf1, oacc[dblk]);
    }

    __syncthreads();
    cur ^= 1;
  }

  // ---- epilogue ----
  const float inv = 1.0f / l_;
  bf16_t* orow = O + ((size_t)(b * SEQ + q)) * DM + h * HD;
  #pragma unroll
  for (int dblk = 0; dblk < 4; ++dblk) {
    bf16x4 ov;
    #pragma unroll
    for (int r = 0; r < 4; ++r) ov[r] = (bf16_t)(oacc[dblk][r] * inv);
    *(bf16x4*)&orow[dblk * 16 + 4 * g] = ov;
  }
}

// ---------------- launch ----------------
extern "C" void kernel_launch(void* const* d_in, const int* in_sizes, int n_in,
                              void* d_out, int out_size, void* d_ws, size_t ws_size,
                              hipStream_t stream)
{
  const float* x  = (const float*)d_in[0];
  const float* Wq = (const float*)d_in[1];
  const float* bq = (const float*)d_in[2];
  const float* Wk = (const float*)d_in[3];
  const float* bk = (const float*)d_in[4];
  const float* Wv = (const float*)d_in[5];
  const float* bv = (const float*)d_in[6];
  const float* Wo = (const float*)d_in[7];
  const float* bo = (const float*)d_in[8];
  float* out = (float*)d_out;

  char* ws = (char*)d_ws;
  size_t off = 0;
  auto alloc = [&](size_t bytes) { char* p = ws + off; off += (bytes + 255) & ~255ULL; return p; };
  bf16_t* xb   = (bf16_t*)alloc((size_t)BS * DM * 2);
  bf16_t* Wcat = (bf16_t*)alloc((size_t)NQKV * DM * 2);
  bf16_t* Wob  = (bf16_t*)alloc((size_t)DM * DM * 2);
  float*  bcat = (float*)alloc((size_t)NQKV * 4);
  float2* rt   = (float2*)alloc((size_t)SEQ * 32 * 8);
  bf16_t* qkv  = (bf16_t*)alloc((size_t)BS * NQKV * 2);
  bf16_t* Qh   = (bf16_t*)alloc((size_t)BS * DM * 2);
  bf16_t* Kh   = (bf16_t*)alloc((size_t)BS * DM * 2);
  bf16_t* Vth  = (bf16_t*)alloc((size_t)BS * DM * 2);
  bf16_t* Oh   = (bf16_t*)alloc((size_t)BS * DM * 2);
  (void)ws_size; (void)in_sizes; (void)n_in; (void)out_size;

  k_cast<<<BS * DM / 8 / 256, 256, 0, stream>>>(x, xb, BS * DM);
  k_cast<<<DM * DM / 8 / 256, 256, 0, stream>>>(Wq, Wcat, DM * DM);
  k_cast<<<DM * DM / 8 / 256, 256, 0, stream>>>(Wk, Wcat + DM * DM, DM * DM);
  k_cast<<<DM * DM / 8 / 256, 256, 0, stream>>>(Wv, Wcat + 2 * DM * DM, DM * DM);
  k_cast<<<DM * DM / 8 / 256, 256, 0, stream>>>(Wo, Wob, DM * DM);
  hipMemcpyAsync(bcat,          bq, DM * 4, hipMemcpyDeviceToDevice, stream);
  hipMemcpyAsync(bcat + DM,     bk, DM * 4, hipMemcpyDeviceToDevice, stream);
  hipMemcpyAsync(bcat + 2 * DM, bv, DM * 4, hipMemcpyDeviceToDevice, stream);
  k_rope_table<<<SEQ * 32 / 256, 256, 0, stream>>>(rt);

  dim3 g1(NQKV / 128, BS / 128);
  k_gemm_bt<0><<<g1, 256, 0, stream>>>(xb, Wcat, bcat, qkv, BS, NQKV, DM);
  k_rope_transpose<<<32 * 32, 256, 0, stream>>>(qkv, rt, Qh, Kh, Vth);
  k_attn<<<32 * 32, 256, 0, stream>>>(Qh, Kh, Vth, Oh);
  dim3 g2(DM / 128, BS / 128);
  k_gemm_bt<1><<<g2, 256, 0, stream>>>(Oh, Wob, bo, out, BS, DM, DM);
}

// Round 4
// 149.221 us; speedup vs baseline: 2.1973x; 1.0247x over previous
//
#include <hip/hip_runtime.h>
#include <hip/hip_bf16.h>
#include <stdint.h>

typedef __bf16 bf16_t;
typedef __bf16 bf16x4 __attribute__((ext_vector_type(4)));
typedef __bf16 bf16x8 __attribute__((ext_vector_type(8)));
typedef float  f32x4  __attribute__((ext_vector_type(4)));

#define DM    1024
#define NH    16
#define HD    64
#define SEQ   2048
#define BATCH 2
#define BS    (BATCH*SEQ)   // 4096
#define NQKV  (3*DM)        // 3072

#define GLOAD_LDS16(g, l) \
  __builtin_amdgcn_global_load_lds((const __attribute__((address_space(1))) void*)(g), \
                                   (__attribute__((address_space(3))) void*)(l), 16, 0, 0)

__device__ __forceinline__ f32x4 mfma16(bf16x8 a, bf16x8 b, f32x4 c) {
  return __builtin_amdgcn_mfma_f32_16x16x32_bf16(a, b, c, 0, 0, 0);
}

// ---------------- cast fp32 -> bf16 (8 elems/thread, vectorized) ----------------
__global__ void k_cast(const float* __restrict__ in, bf16_t* __restrict__ out, int n) {
  int i = (blockIdx.x * blockDim.x + threadIdx.x) * 8;
  if (i >= n) return;
  float4 a = *(const float4*)(in + i);
  float4 b = *(const float4*)(in + i + 4);
  bf16x8 o;
  o[0] = (bf16_t)a.x; o[1] = (bf16_t)a.y; o[2] = (bf16_t)a.z; o[3] = (bf16_t)a.w;
  o[4] = (bf16_t)b.x; o[5] = (bf16_t)b.y; o[6] = (bf16_t)b.z; o[7] = (bf16_t)b.w;
  *(bf16x8*)(out + i) = o;
}

// ---------------- rope cos/sin table: [SEQ][32] float2 ----------------
__global__ void k_rope_table(float2* __restrict__ rt) {
  int idx = blockIdx.x * blockDim.x + threadIdx.x;
  if (idx >= SEQ * 32) return;
  int s = idx >> 5, i = idx & 31;
  float inv = powf(10000.0f, -(float)(2 * i) / 64.0f);
  float ang = (float)s * inv;
  rt[idx] = make_float2(cosf(ang), sinf(ang));
}

// ---------------- GEMM: C[M,N] = A[M,K] * B[N,K]^T + bias ----------------
template<int OUT_F32>
__global__ __launch_bounds__(256) void k_gemm_bt(
    const bf16_t* __restrict__ A, const bf16_t* __restrict__ B,
    const float* __restrict__ bias, void* __restrict__ Cout,
    int M, int N, int K)
{
  __shared__ __align__(16) bf16_t As[128 * 32];
  __shared__ __align__(16) bf16_t Bs[128 * 32];
  const int tid  = threadIdx.x;
  const int lane = tid & 63;
  const int wave = tid >> 6;
  const int wr = wave >> 1, wc = wave & 1;
  const int m0 = blockIdx.y * 128, n0 = blockIdx.x * 128;

  f32x4 acc[4][4];
  #pragma unroll
  for (int i = 0; i < 4; ++i)
    #pragma unroll
    for (int j = 0; j < 4; ++j)
      #pragma unroll
      for (int e = 0; e < 4; ++e) acc[i][j][e] = 0.0f;

  const int srow = wave * 32;
  const int lrow = lane >> 2;
  const int lk   = (lane & 3) * 8;
  const bf16_t* ga0 = A + (size_t)(m0 + srow +      lrow) * K + lk;
  const bf16_t* ga1 = A + (size_t)(m0 + srow + 16 + lrow) * K + lk;
  const bf16_t* gb0 = B + (size_t)(n0 + srow +      lrow) * K + lk;
  const bf16_t* gb1 = B + (size_t)(n0 + srow + 16 + lrow) * K + lk;
  bf16_t* la0 = &As[(srow)      * 32];
  bf16_t* la1 = &As[(srow + 16) * 32];
  bf16_t* lb0 = &Bs[(srow)      * 32];
  bf16_t* lb1 = &Bs[(srow + 16) * 32];

  const bf16_t* pa = &As[(wr * 64 + (lane & 15)) * 32 + (lane >> 4) * 8];
  const bf16_t* pb = &Bs[(wc * 64 + (lane & 15)) * 32 + (lane >> 4) * 8];

  for (int kt = 0; kt < K; kt += 32) {
    GLOAD_LDS16(ga0 + kt, la0);
    GLOAD_LDS16(ga1 + kt, la1);
    GLOAD_LDS16(gb0 + kt, lb0);
    GLOAD_LDS16(gb1 + kt, lb1);
    __syncthreads();
    bf16x8 af[4], bfr[4];
    #pragma unroll
    for (int t = 0; t < 4; ++t) af[t]  = *(const bf16x8*)(pa + t * 16 * 32);
    #pragma unroll
    for (int t = 0; t < 4; ++t) bfr[t] = *(const bf16x8*)(pb + t * 16 * 32);
    #pragma unroll
    for (int i = 0; i < 4; ++i)
      #pragma unroll
      for (int j = 0; j < 4; ++j)
        acc[i][j] = mfma16(af[i], bfr[j], acc[i][j]);
    __syncthreads();
  }

  const int rbase = m0 + wr * 64 + ((lane >> 4) << 2);
  const int cbase = n0 + wc * 64 + (lane & 15);
  #pragma unroll
  for (int j = 0; j < 4; ++j) {
    const int c = cbase + j * 16;
    const float bv = bias[c];
    #pragma unroll
    for (int i = 0; i < 4; ++i) {
      #pragma unroll
      for (int e = 0; e < 4; ++e) {
        const int r = rbase + i * 16 + e;
        float v = acc[i][j][e] + bv;
        if (OUT_F32) ((float*)Cout)[(size_t)r * N + c] = v;
        else         ((bf16_t*)Cout)[(size_t)r * N + c] = (bf16_t)v;
      }
    }
  }
}

// ---------------- RoPE + head split + V transpose ----------------
// Q additionally pre-scaled by 1/sqrt(hd)*log2(e) (folded softmax scale).
__global__ __launch_bounds__(256) void k_rope_transpose(
    const bf16_t* __restrict__ qkv, const float2* __restrict__ rt,
    bf16_t* __restrict__ Qo, bf16_t* __restrict__ Ko, bf16_t* __restrict__ Vt)
{
  __shared__ __align__(16) bf16_t vtile[64][80];
  const int st = blockIdx.x & 31;
  const int bh = blockIdx.x >> 5;
  const int b  = bh >> 4, h = bh & 15;
  const int tid = threadIdx.x;
  const int sl = tid >> 2;
  const int dq = (tid & 3) * 16;
  const int spos = st * 64 + sl;
  const size_t base = ((size_t)(b * SEQ + spos)) * NQKV + h * HD + dq;
  const float SC = 0.125f * 1.44269504088896f;

  bf16x8 q0v = *(const bf16x8*)&qkv[base];
  bf16x8 q1v = *(const bf16x8*)&qkv[base + 8];
  bf16x8 k0v = *(const bf16x8*)&qkv[base + DM];
  bf16x8 k1v = *(const bf16x8*)&qkv[base + DM + 8];
  bf16x8 v0v = *(const bf16x8*)&qkv[base + 2 * DM];
  bf16x8 v1v = *(const bf16x8*)&qkv[base + 2 * DM + 8];

  float qf[16], kf[16];
  #pragma unroll
  for (int e = 0; e < 8; ++e) {
    qf[e] = (float)q0v[e]; qf[8 + e] = (float)q1v[e];
    kf[e] = (float)k0v[e]; kf[8 + e] = (float)k1v[e];
  }
  #pragma unroll
  for (int p = 0; p < 8; ++p) {
    float2 cs = rt[spos * 32 + (dq >> 1) + p];
    float a = qf[2*p], bq_ = qf[2*p+1];
    qf[2*p]   = a * cs.x - bq_ * cs.y;
    qf[2*p+1] = a * cs.y + bq_ * cs.x;
    float c = kf[2*p], d = kf[2*p+1];
    kf[2*p]   = c * cs.x - d * cs.y;
    kf[2*p+1] = c * cs.y + d * cs.x;
  }
  bf16x8 oq0, oq1, ok0, ok1;
  #pragma unroll
  for (int e = 0; e < 8; ++e) {
    oq0[e] = (bf16_t)(qf[e] * SC); oq1[e] = (bf16_t)(qf[8 + e] * SC);
    ok0[e] = (bf16_t)kf[e];        ok1[e] = (bf16_t)kf[8 + e];
  }
  const size_t qdst = ((size_t)bh * SEQ + spos) * HD + dq;
  *(bf16x8*)&Qo[qdst]     = oq0;
  *(bf16x8*)&Qo[qdst + 8] = oq1;
  *(bf16x8*)&Ko[qdst]     = ok0;
  *(bf16x8*)&Ko[qdst + 8] = ok1;

  *(bf16x8*)&vtile[sl][dq]     = v0v;
  *(bf16x8*)&vtile[sl][dq + 8] = v1v;
  __syncthreads();
  const int d  = tid >> 2;
  const int sc = (tid & 3) * 16;
  bf16x8 o0, o1;
  #pragma unroll
  for (int e = 0; e < 8; ++e) {
    o0[e] = vtile[sc + e][d];
    o1[e] = vtile[sc + 8 + e][d];
  }
  const size_t vdst = ((size_t)bh * HD + d) * SEQ + st * 64 + sc;
  *(bf16x8*)&Vt[vdst]     = o0;
  *(bf16x8*)&Vt[vdst + 8] = o1;
}

// ---------------- flash attention (LDS-staged K/V, double-buffered, swapped QK^T) ----
// 4 waves/block, wave owns 16 q rows, KVBLK=64. LDS exactly 40 KiB -> 4 blocks/CU.
// K/V via global_load_lds (linear dest, XOR-swizzled global source); P-tile XOR-
// swizzled [16][64]. Softmax lane-local + T13 defer-rescale; T5 setprio on MFMA.
__global__ __launch_bounds__(256) void k_attn(
    const bf16_t* __restrict__ Q, const bf16_t* __restrict__ K,
    const bf16_t* __restrict__ Vt, bf16_t* __restrict__ O)
{
  __shared__ __align__(16) bf16_t kbuf[2][64 * 64];
  __shared__ __align__(16) bf16_t vbuf[2][64 * 64];
  __shared__ __align__(16) bf16_t plds[4][16 * 64];
  const int tid = threadIdx.x, lane = tid & 63, wave = tid >> 6;
  const int qt = 31 - (blockIdx.x >> 5);   // heavy-first (LPT)
  const int bh = blockIdx.x & 31;
  const int b  = bh >> 4, h = bh & 15;
  const int q0 = qt * 64 + wave * 16;
  const int c16 = lane & 15;
  const int g   = lane >> 4;
  const int q   = q0 + c16;

  const bf16_t* Qb = Q  + (size_t)bh * SEQ * HD;
  const bf16_t* Kb = K  + (size_t)bh * SEQ * HD;
  const bf16_t* Vb = Vt + (size_t)bh * HD * SEQ;

  bf16x8 qf0 = *(const bf16x8*)&Qb[(size_t)q * HD + g * 8];
  bf16x8 qf1 = *(const bf16x8*)&Qb[(size_t)q * HD + 32 + g * 8];

  f32x4 oacc[4];
  #pragma unroll
  for (int dblk = 0; dblk < 4; ++dblk)
    #pragma unroll
    for (int e = 0; e < 4; ++e) oacc[dblk][e] = 0.0f;
  float m_ = -1e30f, l_ = 0.0f;

  const int ntile = qt + 1;
  bf16_t* pl = &plds[wave][0];

  auto stage = [&](int tt, int bb) {
    const int kvs = tt * 64;
    #pragma unroll
    for (int c = 0; c < 2; ++c) {
      const int base = wave * 1024 + c * 4096;        // byte base (wave-uniform)
      const int off  = base + lane * 16;              // this lane's dest byte
      const int row  = off >> 7;
      const int colb = (off & 127) ^ ((row & 7) << 4);
      GLOAD_LDS16(&Kb[(size_t)(kvs + row) * HD + (colb >> 1)], &kbuf[bb][base >> 1]);
      GLOAD_LDS16(&Vb[(size_t)row * SEQ + kvs + (colb >> 1)], &vbuf[bb][base >> 1]);
    }
  };

  stage(0, 0);
  __syncthreads();
  int cur = 0;

  // lane-constant swizzled fragment element offsets for K/V tiles
  const int sw = (c16 & 7) << 4;
  const int e0 = ((16 * g) ^ sw) >> 1;
  const int e1 = ((64 + 16 * g) ^ sw) >> 1;
  // P-tile swizzle (bf16-element units, row = c16)
  const int psw = (c16 & 7) << 3;

  for (int t = 0; t < ntile; ++t) {
    if (t + 1 < ntile) stage(t + 1, cur ^ 1);

    // ---- QK^T (swapped): st[u][r] = S[t*64+16u+4g+r][q] ----
    const bf16_t* kb = kbuf[cur];
    f32x4 st[4];
    __builtin_amdgcn_s_setprio(1);
    #pragma unroll
    for (int u = 0; u < 4; ++u) {
      const int r = 16 * u + c16;
      bf16x8 k0 = *(const bf16x8*)&kb[r * 64 + e0];
      bf16x8 k1 = *(const bf16x8*)&kb[r * 64 + e1];
      f32x4 z; z[0] = z[1] = z[2] = z[3] = 0.0f;
      z = mfma16(k0, qf0, z);
      z = mfma16(k1, qf1, z);
      st[u] = z;
    }
    __builtin_amdgcn_s_setprio(0);

    // ---- V fragments (independent of softmax; issue early) ----
    const bf16_t* vb = vbuf[cur];
    bf16x8 vf[4][2];
    #pragma unroll
    for (int dblk = 0; dblk < 4; ++dblk) {
      const int rv = dblk * 16 + c16;
      vf[dblk][0] = *(const bf16x8*)&vb[rv * 64 + e0];
      vf[dblk][1] = *(const bf16x8*)&vb[rv * 64 + e1];
    }

    // ---- mask (scale already folded into Q); only diagonal tile compares ----
    float pv[16];
    if (t == qt) {
      const int kv0 = t * 64;
      #pragma unroll
      for (int u = 0; u < 4; ++u)
        #pragma unroll
        for (int r = 0; r < 4; ++r) {
          const int kv = kv0 + 16 * u + 4 * g + r;
          pv[u * 4 + r] = (kv <= q) ? st[u][r] : -1e30f;
        }
    } else {
      #pragma unroll
      for (int u = 0; u < 4; ++u)
        #pragma unroll
        for (int r = 0; r < 4; ++r)
          pv[u * 4 + r] = st[u][r];
    }

    // ---- row max: in-register tree + 2 shfl ----
    float ma = fmaxf(fmaxf(pv[0], pv[1]), fmaxf(pv[2], pv[3]));
    float mb = fmaxf(fmaxf(pv[4], pv[5]), fmaxf(pv[6], pv[7]));
    float mc = fmaxf(fmaxf(pv[8], pv[9]), fmaxf(pv[10], pv[11]));
    float md = fmaxf(fmaxf(pv[12], pv[13]), fmaxf(pv[14], pv[15]));
    float mx = fmaxf(fmaxf(ma, mb), fmaxf(mc, md));
    mx = fmaxf(mx, __shfl_xor(mx, 16));
    mx = fmaxf(mx, __shfl_xor(mx, 32));

    // ---- T13 defer-rescale ----
    if (__any(mx - m_ > 12.0f)) {
      const float mn = fmaxf(m_, mx);
      const float alpha = exp2f(m_ - mn);
      l_ *= alpha;
      #pragma unroll
      for (int dblk = 0; dblk < 4; ++dblk)
        #pragma unroll
        for (int e = 0; e < 4; ++e) oacc[dblk][e] *= alpha;
      m_ = mn;
    }

    // ---- exp + row sum ----
    #pragma unroll
    for (int i = 0; i < 16; ++i) pv[i] = exp2f(pv[i] - m_);
    float s0 = (pv[0] + pv[1]) + (pv[2] + pv[3]);
    float s1 = (pv[4] + pv[5]) + (pv[6] + pv[7]);
    float s2 = (pv[8] + pv[9]) + (pv[10] + pv[11]);
    float s3 = (pv[12] + pv[13]) + (pv[14] + pv[15]);
    float ps = (s0 + s1) + (s2 + s3);
    ps += __shfl_xor(ps, 16);
    ps += __shfl_xor(ps, 32);
    l_ += ps;

    // ---- pack P -> bf16, swizzled per-wave LDS round-trip ----
    #pragma unroll
    for (int u = 0; u < 4; ++u) {
      bf16x4 pk;
      #pragma unroll
      for (int r = 0; r < 4; ++r) pk[r] = (bf16_t)pv[u * 4 + r];
      *(bf16x4*)&pl[c16 * 64 + ((16 * u + 4 * g) ^ psw)] = pk;
    }
    bf16x8 pf0 = *(const bf16x8*)&pl[c16 * 64 + ((8 * g) ^ psw)];
    bf16x8 pf1 = *(const bf16x8*)&pl[c16 * 64 + ((32 + 8 * g) ^ psw)];

    // ---- PV: oacc[dblk][r] = O[d = dblk*16+4g+r][q] ----
    __builtin_amdgcn_s_setprio(1);
    #pragma unroll
    for (int dblk = 0; dblk < 4; ++dblk) {
      oacc[dblk] = mfma16(vf[dblk][0], pf0, oacc[dblk]);
      oacc[dblk] = mfma16(vf[dblk][1], pf1, oacc[dblk]);
    }
    __builtin_amdgcn_s_setprio(0);

    __syncthreads();
    cur ^= 1;
  }

  // ---- epilogue ----
  const float inv = 1.0f / l_;
  bf16_t* orow = O + ((size_t)(b * SEQ + q)) * DM + h * HD;
  #pragma unroll
  for (int dblk = 0; dblk < 4; ++dblk) {
    bf16x4 ov;
    #pragma unroll
    for (int r = 0; r < 4; ++r) ov[r] = (bf16_t)(oacc[dblk][r] * inv);
    *(bf16x4*)&orow[dblk * 16 + 4 * g] = ov;
  }
}

// ---------------- launch ----------------
extern "C" void kernel_launch(void* const* d_in, const int* in_sizes, int n_in,
                              void* d_out, int out_size, void* d_ws, size_t ws_size,
                              hipStream_t stream)
{
  const float* x  = (const float*)d_in[0];
  const float* Wq = (const float*)d_in[1];
  const float* bq = (const float*)d_in[2];
  const float* Wk = (const float*)d_in[3];
  const float* bk = (const float*)d_in[4];
  const float* Wv = (const float*)d_in[5];
  const float* bv = (const float*)d_in[6];
  const float* Wo = (const float*)d_in[7];
  const float* bo = (const float*)d_in[8];
  float* out = (float*)d_out;

  char* ws = (char*)d_ws;
  size_t off = 0;
  auto alloc = [&](size_t bytes) { char* p = ws + off; off += (bytes + 255) & ~255ULL; return p; };
  bf16_t* xb   = (bf16_t*)alloc((size_t)BS * DM * 2);
  bf16_t* Wcat = (bf16_t*)alloc((size_t)NQKV * DM * 2);
  bf16_t* Wob  = (bf16_t*)alloc((size_t)DM * DM * 2);
  float*  bcat = (float*)alloc((size_t)NQKV * 4);
  float2* rt   = (float2*)alloc((size_t)SEQ * 32 * 8);
  bf16_t* qkv  = (bf16_t*)alloc((size_t)BS * NQKV * 2);
  bf16_t* Qh   = (bf16_t*)alloc((size_t)BS * DM * 2);
  bf16_t* Kh   = (bf16_t*)alloc((size_t)BS * DM * 2);
  bf16_t* Vth  = (bf16_t*)alloc((size_t)BS * DM * 2);
  bf16_t* Oh   = (bf16_t*)alloc((size_t)BS * DM * 2);
  (void)ws_size; (void)in_sizes; (void)n_in; (void)out_size;

  k_cast<<<BS * DM / 8 / 256, 256, 0, stream>>>(x, xb, BS * DM);
  k_cast<<<DM * DM / 8 / 256, 256, 0, stream>>>(Wq, Wcat, DM * DM);
  k_cast<<<DM * DM / 8 / 256, 256, 0, stream>>>(Wk, Wcat + DM * DM, DM * DM);
  k_cast<<<DM * DM / 8 / 256, 256, 0, stream>>>(Wv, Wcat + 2 * DM * DM, DM * DM);
  k_cast<<<DM * DM / 8 / 256, 256, 0, stream>>>(Wo, Wob, DM * DM);
  hipMemcpyAsync(bcat,          bq, DM * 4, hipMemcpyDeviceToDevice, stream);
  hipMemcpyAsync(bcat + DM,     bk, DM * 4, hipMemcpyDeviceToDevice, stream);
  hipMemcpyAsync(bcat + 2 * DM, bv, DM * 4, hipMemcpyDeviceToDevice, stream);
  k_rope_table<<<SEQ * 32 / 256, 256, 0, stream>>>(rt);

  dim3 g1(NQKV / 128, BS / 128);
  k_gemm_bt<0><<<g1, 256, 0, stream>>>(xb, Wcat, bcat, qkv, BS, NQKV, DM);
  k_rope_transpose<<<32 * 32, 256, 0, stream>>>(qkv, rt, Qh, Kh, Vth);
  k_attn<<<32 * 32, 256, 0, stream>>>(Qh, Kh, Vth, Oh);
  dim3 g2(DM / 128, BS / 128);
  k_gemm_bt<1><<<g2, 256, 0, stream>>>(Oh, Wob, bo, out, BS, DM, DM);
}